// Round 3
// baseline (294.265 us; speedup 1.0000x reference)
//
#include <hip/hip_runtime.h>

// RGBuvHistBlock: x (8,3,65536) f32 -> normalized uv histograms (8,3,64,64) f32.
// hist[b,c,h,g] = sum_n Iy*ku[h] * kv[g]; normalize per batch.

constexpr int   HBINS  = 64;
constexpr float EPSF   = 1e-6f;
constexpr int   BATCH  = 8;
constexpr int   NPIX   = 65536;
constexpr int   NBC    = 24;                 // 8 batches * 3 channels
constexpr int   CHUNKS = 64;                 // pixel chunks per (b,c)
constexpr int   PIX_PER_BLOCK = NPIX / CHUNKS;  // 1024
constexpr int   PX     = 16;                 // pixels staged per iteration
constexpr int   ROW    = HBINS + 4;          // padded LDS row (bank-conflict-free)

__global__ __launch_bounds__(256) void hist_kernel(const float* __restrict__ x,
                                                   float* __restrict__ ws) {
    const int bc = blockIdx.y;               // 0..23
    const int b  = bc / 3;
    const int c  = bc - b * 3;
    const int t  = threadIdx.x;

    __shared__ float wu_s[PX][ROW];
    __shared__ float kv_s[PX][ROW];

    float acc[4][4];
#pragma unroll
    for (int i = 0; i < 4; ++i)
#pragma unroll
        for (int j = 0; j < 4; ++j) acc[i][j] = 0.0f;

    const float* xr = x + ((size_t)b * 3 + 0) * NPIX;
    const float* xg = x + ((size_t)b * 3 + 1) * NPIX;
    const float* xb = x + ((size_t)b * 3 + 2) * NPIX;

    const int pix0 = blockIdx.x * PIX_PER_BLOCK;

    // producer mapping: 16 pixels x 16 slots; slot 0..7 -> wu bins, 8..15 -> kv bins
    const int p_local = t & (PX - 1);
    const int slot    = t >> 4;              // 0..15 (wave-uniform)
    const int is_kv   = slot >> 3;           // waves 0-1: wu, waves 2-3: kv
    const int hb      = (slot & 7) * 8;      // base bin of this thread's 8 values

    // consumer mapping: thread owns 4x4 tile at (h0, g0)
    const int h0 = (t & 15) * 4;
    const int g0 = (t >> 4) * 4;

    // lin[i]/sigma: lin = -3 + i*(6/63); /sigma(=0.02) -> -150 + i*(300/63)
    const float binstep  = 300.0f / 63.0f;
    const float base_lin = (float)hb * binstep - 150.0f;

    for (int p0 = 0; p0 < PIX_PER_BLOCK; p0 += PX) {
        // ---- produce wu/kv for PX pixels ----
        const int pix = pix0 + p0 + p_local;
        float r  = xr[pix];
        float g  = xg[pix];
        float bl = xb[pix];
        r  = fminf(fmaxf(fmaf(r, 0.5f, 0.5f), 0.0f), 1.0f);
        g  = fminf(fmaxf(fmaf(g, 0.5f, 0.5f), 0.0f), 1.0f);
        bl = fminf(fmaxf(fmaf(bl, 0.5f, 0.5f), 0.0f), 1.0f);

        const float lr = __logf(r + EPSF);
        const float lg = __logf(g + EPSF);
        const float lb = __logf(bl + EPSF);

        float lc, lu, lv;
        if (c == 0)      { lc = lr; lu = lg; lv = lb; }   // u = r-g, v = r-b
        else if (c == 1) { lc = lg; lu = lr; lv = lb; }   // u = g-r, v = g-b
        else             { lc = lb; lu = lr; lv = lg; }   // u = b-r, v = b-g

        const float coord = is_kv ? (lc - lv) : (lc - lu);
        const float Iy    = __builtin_amdgcn_sqrtf(fmaf(r, r, fmaf(g, g, fmaf(bl, bl, EPSF))));
        const float scale = is_kv ? 1.0f : Iy;

        const float cs0 = fmaf(coord, 50.0f, -base_lin);   // (coord - lin[hb]) / sigma
        float vals[8];
#pragma unroll
        for (int k = 0; k < 8; ++k) {
            const float d = cs0 - (float)k * binstep;
            vals[k] = scale * __builtin_amdgcn_rcpf(fmaf(d, d, 1.0f));
        }

        __syncthreads();   // previous consume phase done before overwriting LDS
        float* dst = is_kv ? &kv_s[p_local][hb] : &wu_s[p_local][hb];
        *(float4*)(dst)     = make_float4(vals[0], vals[1], vals[2], vals[3]);
        *(float4*)(dst + 4) = make_float4(vals[4], vals[5], vals[6], vals[7]);
        __syncthreads();

        // ---- consume: rank-1 updates of the 64x64 tile ----
#pragma unroll
        for (int p = 0; p < PX; ++p) {
            const float4 a = *(const float4*)&wu_s[p][h0];
            const float4 v = *(const float4*)&kv_s[p][g0];
            const float av[4] = {a.x, a.y, a.z, a.w};
            const float vv[4] = {v.x, v.y, v.z, v.w};
#pragma unroll
            for (int i = 0; i < 4; ++i)
#pragma unroll
                for (int j = 0; j < 4; ++j)
                    acc[i][j] = fmaf(av[i], vv[j], acc[i][j]);
        }
    }

    float* hist = ws + (size_t)bc * HBINS * HBINS;
#pragma unroll
    for (int i = 0; i < 4; ++i)
#pragma unroll
        for (int j = 0; j < 4; ++j)
            atomicAdd(&hist[(h0 + i) * HBINS + (g0 + j)], acc[i][j]);
}

__global__ __launch_bounds__(256) void norm_kernel(const float* __restrict__ ws,
                                                   float* __restrict__ out) {
    const int b = blockIdx.x;
    const float* h = ws  + (size_t)b * 3 * HBINS * HBINS;
    float*       o = out + (size_t)b * 3 * HBINS * HBINS;
    const int t = threadIdx.x;
    const int n = 3 * HBINS * HBINS;   // 12288

    float s = 0.0f;
    for (int i = t; i < n; i += 256) s += h[i];
#pragma unroll
    for (int off = 32; off > 0; off >>= 1) s += __shfl_down(s, off, 64);

    __shared__ float partial[4];
    if ((t & 63) == 0) partial[t >> 6] = s;
    __syncthreads();
    const float total = partial[0] + partial[1] + partial[2] + partial[3];
    const float inv = 1.0f / (total + EPSF);

    for (int i = t; i < n; i += 256) o[i] = h[i] * inv;
}

extern "C" void kernel_launch(void* const* d_in, const int* in_sizes, int n_in,
                              void* d_out, int out_size, void* d_ws, size_t ws_size,
                              hipStream_t stream) {
    const float* x   = (const float*)d_in[0];
    float*       out = (float*)d_out;
    float*       ws  = (float*)d_ws;

    // zero the fp32 histogram accumulators (ws is poisoned each call)
    hipMemsetAsync(ws, 0, (size_t)NBC * HBINS * HBINS * sizeof(float), stream);

    dim3 grid(CHUNKS, NBC);
    hist_kernel<<<grid, 256, 0, stream>>>(x, ws);
    norm_kernel<<<BATCH, 256, 0, stream>>>(ws, out);
}

// Round 6
// 169.140 us; speedup vs baseline: 1.7398x; 1.7398x over previous
//
#include <hip/hip_runtime.h>
#include <hip/hip_bf16.h>

// RGBuvHistBlock: x (8,3,65536) f32 -> normalized uv histograms (8,3,64,64) f32.
// hist[b,c,h,g] = sum_p (Iy*ku[h]) * kv[g]  == Wu^T (64xN) * Kv (Nx64) GEMM.
// MFMA consumer with fragments computed directly in registers (no wu/kv LDS).

typedef __bf16 bf16x8 __attribute__((ext_vector_type(8)));
typedef float  f32x4  __attribute__((ext_vector_type(4)));

constexpr int   HBINS = 64;
constexpr float EPSF  = 1e-6f;
constexpr int   BATCH = 8;
constexpr int   NPIX  = 65536;
constexpr int   NBC   = 24;                  // 8 batches * 3 channels
constexpr int   CHUNKS = 32;                 // pixel chunks per (b,c)
constexpr int   PPC   = NPIX / CHUNKS;       // 2048 pixels per block
constexpr int   PITER = 256;                 // pixels staged per block-iteration
constexpr float BINSTEP  = 300.0f / 63.0f;   // lin[i]/sigma step
constexpr float LOGSCALE = 34.6573590279973f; // 50 * ln(2): log2-diff -> (ln-diff)/sigma

__global__ __launch_bounds__(256, 3) void hist_kernel(const float* __restrict__ x,
                                                      float* __restrict__ ws) {
    const int bc   = blockIdx.y;             // 0..23
    const int b    = bc / 3;
    const int c    = bc - b * 3;
    const int t    = threadIdx.x;
    const int lane = t & 63;
    const int w    = t >> 6;                 // wave 0..3
    const int kgrp = lane >> 4;              // 0..3
    const int l16  = lane & 15;

    __shared__ float cu_s[PITER];
    __shared__ float cv_s[PITER];
    __shared__ float iy_s[PITER];
    __shared__ float lhist[HBINS * HBINS];   // 16 KB block-level accumulator

    for (int i = t; i < HBINS * HBINS; i += 256) lhist[i] = 0.0f;

    f32x4 acc[4][4];
#pragma unroll
    for (int m = 0; m < 4; ++m)
#pragma unroll
        for (int n = 0; n < 4; ++n) acc[m][n] = (f32x4){0.f, 0.f, 0.f, 0.f};

    const float* xr = x + ((size_t)b * 3 + 0) * NPIX;
    const float* xg = x + ((size_t)b * 3 + 1) * NPIX;
    const float* xb = x + ((size_t)b * 3 + 2) * NPIX;
    const int pix0 = blockIdx.x * PPC;

    for (int base = 0; base < PPC; base += PITER) {
        // ---- stage per-pixel coords: one pixel per thread ----
        const int p = pix0 + base + t;
        float r  = xr[p], g = xg[p], bl = xb[p];
        r  = fminf(fmaxf(fmaf(r,  0.5f, 0.5f), 0.0f), 1.0f);
        g  = fminf(fmaxf(fmaf(g,  0.5f, 0.5f), 0.0f), 1.0f);
        bl = fminf(fmaxf(fmaf(bl, 0.5f, 0.5f), 0.0f), 1.0f);

        const float l2r = __log2f(r  + EPSF);
        const float l2g = __log2f(g  + EPSF);
        const float l2b = __log2f(bl + EPSF);

        float lc, lu, lv;
        if (c == 0)      { lc = l2r; lu = l2g; lv = l2b; }  // u=r-g, v=r-b
        else if (c == 1) { lc = l2g; lu = l2r; lv = l2b; }  // u=g-r, v=g-b
        else             { lc = l2b; lu = l2r; lv = l2g; }  // u=b-r, v=b-g

        const float cu = (lc - lu) * LOGSCALE;   // coord_u / sigma
        const float cv = (lc - lv) * LOGSCALE;   // coord_v / sigma
        const float iy = __builtin_amdgcn_sqrtf(fmaf(r, r, fmaf(g, g, fmaf(bl, bl, EPSF))));

        __syncthreads();                 // previous iter's consumers done
        cu_s[t] = cu; cv_s[t] = cv; iy_s[t] = iy;
        __syncthreads();                 // coords visible

        // ---- consume: wave w owns pixels [w*64, w*64+64) as two K=32 steps ----
#pragma unroll
        for (int ks = 0; ks < 2; ++ks) {
            const int k0 = w * 64 + ks * 32 + kgrp * 8;   // 8-aligned
            float cu8[8], cv8[8], iy8[8];
            *(float4*)&cu8[0] = *(const float4*)&cu_s[k0];
            *(float4*)&cu8[4] = *(const float4*)&cu_s[k0 + 4];
            *(float4*)&cv8[0] = *(const float4*)&cv_s[k0];
            *(float4*)&cv8[4] = *(const float4*)&cv_s[k0 + 4];
            *(float4*)&iy8[0] = *(const float4*)&iy_s[k0];
            *(float4*)&iy8[4] = *(const float4*)&iy_s[k0 + 4];

            // B fragments: kv at bins g = n*16 + l16 (no Iy scale)
            bf16x8 bfr[4];
#pragma unroll
            for (int n = 0; n < 4; ++n) {
                const float ling = (float)(n * 16 + l16) * BINSTEP - 150.0f;
#pragma unroll
                for (int j = 0; j < 8; ++j) {
                    const float d = cv8[j] - ling;
                    bfr[n][j] = (__bf16)__builtin_amdgcn_rcpf(fmaf(d, d, 1.0f));
                }
            }
            // A fragments: wu = Iy*ku at bins h = m*16 + l16, then 4 MFMAs each
#pragma unroll
            for (int m = 0; m < 4; ++m) {
                const float linh = (float)(m * 16 + l16) * BINSTEP - 150.0f;
                bf16x8 af;
#pragma unroll
                for (int j = 0; j < 8; ++j) {
                    const float d = cu8[j] - linh;
                    af[j] = (__bf16)(iy8[j] * __builtin_amdgcn_rcpf(fmaf(d, d, 1.0f)));
                }
#pragma unroll
                for (int n = 0; n < 4; ++n)
                    acc[m][n] = __builtin_amdgcn_mfma_f32_16x16x32_bf16(af, bfr[n], acc[m][n], 0, 0, 0);
            }
        }
    }

    // ---- block reduction: 4 waves -> lhist, then one flush to global ----
    __syncthreads();
    const int crow = kgrp * 4;   // C/D: col = lane&15, row = (lane>>4)*4 + ri  [m89]
#pragma unroll
    for (int m = 0; m < 4; ++m)
#pragma unroll
        for (int n = 0; n < 4; ++n)
#pragma unroll
            for (int ri = 0; ri < 4; ++ri)
                atomicAdd(&lhist[(m * 16 + crow + ri) * HBINS + n * 16 + l16], acc[m][n][ri]);
    __syncthreads();

    float* gh = ws + (size_t)bc * HBINS * HBINS;
    for (int i = t; i < HBINS * HBINS; i += 256) atomicAdd(&gh[i], lhist[i]);
}

__global__ __launch_bounds__(256) void norm_kernel(const float* __restrict__ ws,
                                                   float* __restrict__ out) {
    const int b = blockIdx.x;
    const float* h = ws  + (size_t)b * 3 * HBINS * HBINS;
    float*       o = out + (size_t)b * 3 * HBINS * HBINS;
    const int t = threadIdx.x;
    const int n = 3 * HBINS * HBINS;   // 12288

    float s = 0.0f;
    for (int i = t; i < n; i += 256) s += h[i];
#pragma unroll
    for (int off = 32; off > 0; off >>= 1) s += __shfl_down(s, off, 64);

    __shared__ float partial[4];
    if ((t & 63) == 0) partial[t >> 6] = s;
    __syncthreads();
    const float total = partial[0] + partial[1] + partial[2] + partial[3];
    const float inv = 1.0f / (total + EPSF);

    for (int i = t; i < n; i += 256) o[i] = h[i] * inv;
}

extern "C" void kernel_launch(void* const* d_in, const int* in_sizes, int n_in,
                              void* d_out, int out_size, void* d_ws, size_t ws_size,
                              hipStream_t stream) {
    const float* x   = (const float*)d_in[0];
    float*       out = (float*)d_out;
    float*       ws  = (float*)d_ws;

    // zero the fp32 histogram accumulators (ws is poisoned each call)
    hipMemsetAsync(ws, 0, (size_t)NBC * HBINS * HBINS * sizeof(float), stream);

    dim3 grid(CHUNKS, NBC);
    hist_kernel<<<grid, 256, 0, stream>>>(x, ws);
    norm_kernel<<<BATCH, 256, 0, stream>>>(ws, out);
}